// Round 3
// baseline (8861.518 us; speedup 1.0000x reference)
//
#include <hip/hip_runtime.h>
#include <hip/hip_bf16.h>

// MCMambaLM: B=1, T=2048, D=768, K=8, V=1024, D_IN=1536, D_STATE=16,
// D_CONV=4, DT_RANK=48, L=4, SEG=256, n_seg=8.
// Input dtype (f32 vs bf16) detected at runtime from D_skip (== ones):
// first 4 bytes are 0x3F800000 (f32) vs 0x3F803F80 (bf16). All weights are
// converted to f32 in static scratch; compute is f32; output stored per flag.

#define T_LEN   2048
#define DMODEL  768
#define DIN     1536
#define DXZ     3072
#define NSTATE  16
#define DTRANK  48
#define FDIM    80      // DT_RANK + 2*D_STATE
#define NSEG    8
#define SEGLEN  256
#define NHEADV  8192    // K*V

// ---- activations (floats) ----
#define OFF_X     0u
#define OFF_XZ    1572864u
#define OFF_UC    7864320u
#define OFF_DBC   11010048u
#define OFF_DELTA 11173888u
#define OFF_Y     14319616u
#define OFF_XOUT  17465344u
#define OFF_URET  19038208u
#define OFF_MCUR  20611072u
#define OFF_MSTK  22183936u
// ---- converted f32 weights ----
#define OFF_WEMB  22190080u   // 8*1024*768
#define OFF_WWU   28481536u   // 4*768*768
#define OFF_WIP   30840832u   // 4*3072*768
#define OFF_WCW   40278016u   // 4*1536*4
#define OFF_WCB   40302592u   // 4*1536
#define OFF_WXP   40308736u   // 4*80*1536
#define OFF_WDW   40800256u   // 4*1536*48
#define OFF_WDB   41095168u   // 4*1536
#define OFF_WAL   41101312u   // 4*1536*16
#define OFF_WDS   41199616u   // 4*1536
#define OFF_WOP   41205760u   // 4*768*1536
#define OFF_WHW   45924352u   // 8192*768
#define WS_TOTAL  52215808u   // ~199 MiB
__device__ __align__(16) float g_ws[WS_TOTAL];
__device__ unsigned int g_isbf16;

__device__ __forceinline__ float bf2f(unsigned short u) {
  union { unsigned int i; float f; } c; c.i = ((unsigned int)u) << 16; return c.f;
}
__device__ __forceinline__ unsigned short f2bf(float f) {
  union { float f; unsigned int i; } c; c.f = f;
  unsigned int lsb = (c.i >> 16) & 1u;
  unsigned int r = c.i + 0x7fffu + lsb;
  return (unsigned short)(r >> 16);
}
__device__ __forceinline__ float softplusf(float v) {
  return v > 0.f ? v + log1pf(expf(-v)) : log1pf(expf(v));
}

// ---------------- dtype detect ----------------
__global__ void detect_kernel(const unsigned int* __restrict__ dsk) {
  if (threadIdx.x == 0 && blockIdx.x == 0)
    g_isbf16 = (dsk[0] == 0x3F803F80u) ? 1u : 0u;
}

// ---------------- weight convert (bf16 or f32 -> f32 in g_ws) ----------------
__global__ __launch_bounds__(256) void convert_kernel(
    const void* __restrict__ src, unsigned int dstoff, int n) {
  int stride = gridDim.x * 256;
  bool isb = (g_isbf16 != 0u);
  for (int i = blockIdx.x * 256 + threadIdx.x; i < n; i += stride) {
    float v = isb ? bf2f(((const unsigned short*)src)[i])
                  : ((const float*)src)[i];
    g_ws[dstoff + i] = v;
  }
}

// ---------------- embedding ----------------
__global__ __launch_bounds__(256) void embed_kernel(const int* __restrict__ tokens) {
  int t = blockIdx.x;
  int tid = threadIdx.x;
  const float* __restrict__ emb = g_ws + OFF_WEMB;
  int tok[8];
#pragma unroll
  for (int k = 0; k < 8; ++k) tok[k] = tokens[t * 8 + k];
#pragma unroll
  for (int j = 0; j < 3; ++j) {
    int d = tid + j * 256;
    float s = 0.f;
#pragma unroll
    for (int k = 0; k < 8; ++k)
      s += emb[((size_t)k * 1024 + tok[k]) * DMODEL + d];
    g_ws[OFF_X + (size_t)t * DMODEL + d] = s;
  }
}

// ------- generic NT GEMM: C[M,N] = A[M,K] (f32 ws) * B[N,K]^T (f32 ws) -------
// EPI: 0 = store f32 to ws, 1 = softplus(acc + bias) f32 to ws,
//      2 = store to d_out (bf16 or f32 per g_isbf16)
template <int EPI>
__global__ __launch_bounds__(256) void gemm_nt(
    unsigned int aoff, int lda, unsigned int boff, int ldb,
    unsigned int coff, void* __restrict__ Cout, int ldc,
    int M, int N, int K, unsigned int biasoff) {
  const float* __restrict__ A = g_ws + aoff;
  const float* __restrict__ Bw = g_ws + boff;
  __shared__ float As[16][68];
  __shared__ float Bs[16][68];
  int tid = threadIdx.x;
  int bx = blockIdx.x, by = blockIdx.y;
  int tx = tid & 15, ty = tid >> 4;
  int lr = tid >> 2;          // 0..63 (tile row/col for loads)
  int lc = (tid & 3) * 4;     // 0,4,8,12 (k offset for loads)
  float acc[4][4] = {};
  for (int k0 = 0; k0 < K; k0 += 16) {
    const float* ap = A + (size_t)(by * 64 + lr) * lda + k0 + lc;
    float4 av = *reinterpret_cast<const float4*>(ap);
    As[lc + 0][lr] = av.x; As[lc + 1][lr] = av.y;
    As[lc + 2][lr] = av.z; As[lc + 3][lr] = av.w;
    int bn = bx * 64 + lr;
    float4 bv = make_float4(0.f, 0.f, 0.f, 0.f);
    if (bn < N)
      bv = *reinterpret_cast<const float4*>(Bw + (size_t)bn * ldb + k0 + lc);
    Bs[lc + 0][lr] = bv.x; Bs[lc + 1][lr] = bv.y;
    Bs[lc + 2][lr] = bv.z; Bs[lc + 3][lr] = bv.w;
    __syncthreads();
#pragma unroll
    for (int kk = 0; kk < 16; ++kk) {
      float4 a = *reinterpret_cast<const float4*>(&As[kk][ty * 4]);
      float4 b = *reinterpret_cast<const float4*>(&Bs[kk][tx * 4]);
      float ar[4] = {a.x, a.y, a.z, a.w};
      float br[4] = {b.x, b.y, b.z, b.w};
#pragma unroll
      for (int i = 0; i < 4; ++i)
#pragma unroll
        for (int j = 0; j < 4; ++j) acc[i][j] = fmaf(ar[i], br[j], acc[i][j]);
    }
    __syncthreads();
  }
  int m0 = by * 64 + ty * 4, n0 = bx * 64 + tx * 4;
  bool outb = (EPI == 2) && (g_isbf16 != 0u);
#pragma unroll
  for (int i = 0; i < 4; ++i) {
#pragma unroll
    for (int j = 0; j < 4; ++j) {
      int m = m0 + i, n = n0 + j;
      if (n < N) {
        float v = acc[i][j];
        if (EPI == 1) v = softplusf(v + g_ws[biasoff + n]);
        if (EPI == 2) {
          if (outb) ((unsigned short*)Cout)[(size_t)m * ldc + n] = f2bf(v);
          else      ((float*)Cout)[(size_t)m * ldc + n] = v;
        } else {
          g_ws[coff + (size_t)m * ldc + n] = v;
        }
      }
    }
  }
}

// ---------------- depthwise causal conv(4) + SiLU ----------------
__global__ __launch_bounds__(256) void conv_silu_kernel(
    unsigned int cwoff, unsigned int cboff) {
  int idx = blockIdx.x * 256 + threadIdx.x;   // 0 .. T*DIN-1
  int t = idx / DIN, e = idx - t * DIN;
  const float* __restrict__ xz = g_ws + OFF_XZ;
  const float* __restrict__ cw = g_ws + cwoff;
  float w0 = cw[e * 4 + 0], w1 = cw[e * 4 + 1];
  float w2 = cw[e * 4 + 2], w3 = cw[e * 4 + 3];
  float acc = g_ws[cboff + e];
  if (t >= 3) acc = fmaf(w0, xz[(size_t)(t - 3) * DXZ + e], acc);
  if (t >= 2) acc = fmaf(w1, xz[(size_t)(t - 2) * DXZ + e], acc);
  if (t >= 1) acc = fmaf(w2, xz[(size_t)(t - 1) * DXZ + e], acc);
  acc = fmaf(w3, xz[(size_t)t * DXZ + e], acc);
  float sig = 1.f / (1.f + __expf(-acc));
  g_ws[OFF_UC + idx] = acc * sig;
}

// ---------------- selective scan: lane = (channel, state) ----------------
__global__ __launch_bounds__(256) void scan_kernel(
    unsigned int aloff, unsigned int dsoff) {
  int tid = threadIdx.x;
  int s = tid & 15;
  int e = blockIdx.x * 16 + (tid >> 4);
  const float* __restrict__ delta = g_ws + OFF_DELTA;
  const float* __restrict__ uc    = g_ws + OFF_UC;
  const float* __restrict__ dbc   = g_ws + OFF_DBC;
  const float* __restrict__ xz    = g_ws + OFF_XZ;
  float a = -expf(g_ws[aloff + e * NSTATE + s]);   // A = -exp(A_log)
  float dsk = g_ws[dsoff + e];
  float h = 0.f;
  for (int t = 0; t < T_LEN; ++t) {
    float d = delta[(size_t)t * DIN + e];
    float u = uc[(size_t)t * DIN + e];
    float b = dbc[(size_t)t * FDIM + DTRANK + s];
    float c = dbc[(size_t)t * FDIM + DTRANK + NSTATE + s];
    float dA = __expf(d * a);   // d>=0, a<0 -> arg<=0
    h = fmaf(dA, h, d * u * b);
    float yp = h * c;
    yp += __shfl_xor(yp, 1);
    yp += __shfl_xor(yp, 2);
    yp += __shfl_xor(yp, 4);
    yp += __shfl_xor(yp, 8);
    if (s == 0) {
      float z = xz[(size_t)t * DXZ + DIN + e];
      float sig = 1.f / (1.f + __expf(-z));
      g_ws[OFF_Y + (size_t)t * DIN + e] = (yp + dsk * u) * z * sig;
    }
  }
}

// ---------------- segment mean (m_stack) ----------------
__global__ __launch_bounds__(256) void mstack_kernel() {
  int n = blockIdx.x;
  const float* __restrict__ x = g_ws + OFF_X;
  for (int d = threadIdx.x; d < DMODEL; d += 256) {
    float s = 0.f;
    for (int i = 0; i < SEGLEN; ++i)
      s += x[(size_t)(n * SEGLEN + i) * DMODEL + d];
    g_ws[OFF_MSTK + n * DMODEL + d] = s * (1.f / 256.f);
  }
}

// ---------------- running segment mean (m_current) ----------------
__global__ __launch_bounds__(768) void mcurrent_kernel() {
  int n = blockIdx.x;
  int d = threadIdx.x;
  const float* __restrict__ x = g_ws + OFF_X;
  float run = 0.f;
  for (int i = 0; i < SEGLEN; ++i) {
    size_t off = (size_t)(n * SEGLEN + i) * DMODEL + d;
    run += x[off];
    g_ws[OFF_MCUR + off] = run / (float)(i + 1);
  }
}

// ---------------- retention scores + softmax + combine (writes X) ---------
__global__ __launch_bounds__(256) void retention_kernel() {
  int t = blockIdx.x;
  int tid = threadIdx.x;
  const float* __restrict__ xout = g_ws + OFF_XOUT;
  const float* __restrict__ uret = g_ws + OFF_URET;
  const float* __restrict__ mcur = g_ws + OFF_MCUR;
  const float* __restrict__ mstk = g_ws + OFF_MSTK;
  __shared__ float red[4][9];
  __shared__ float attn_s[9];
  float p[9];
#pragma unroll
  for (int n = 0; n < 9; ++n) p[n] = 0.f;
#pragma unroll
  for (int j = 0; j < 3; ++j) {
    int d = tid + j * 256;
    float u = uret[(size_t)t * DMODEL + d];
    p[8] = fmaf(u, mcur[(size_t)t * DMODEL + d], p[8]);
#pragma unroll
    for (int n = 0; n < 8; ++n)
      p[n] = fmaf(u, mstk[n * DMODEL + d], p[n]);
  }
#pragma unroll
  for (int off = 32; off > 0; off >>= 1)
#pragma unroll
    for (int n = 0; n < 9; ++n) p[n] += __shfl_down(p[n], off, 64);
  int wave = tid >> 6;
  if ((tid & 63) == 0)
#pragma unroll
    for (int n = 0; n < 9; ++n) red[wave][n] = p[n];
  __syncthreads();
  if (tid == 0) {
    const float scale = 0.03608439182435161f;  // 1/sqrt(768)
    int seg = t >> 8;
    float sc[9], mx = -3.0e38f;
#pragma unroll
    for (int n = 0; n < 9; ++n) {
      float v = (red[0][n] + red[1][n] + red[2][n] + red[3][n]) * scale;
      if (n < 8 && n >= seg) v = -1e30f;   // keep only n < seg
      sc[n] = v;
      mx = fmaxf(mx, v);
    }
    float den = 0.f;
#pragma unroll
    for (int n = 0; n < 9; ++n) {
      float e = __expf(sc[n] - mx);
      sc[n] = e;
      den += e;
    }
    float inv = 1.f / den;
#pragma unroll
    for (int n = 0; n < 9; ++n) attn_s[n] = sc[n] * inv;
  }
  __syncthreads();
  float a[9];
#pragma unroll
  for (int n = 0; n < 9; ++n) a[n] = attn_s[n];
#pragma unroll
  for (int j = 0; j < 3; ++j) {
    int d = tid + j * 256;
    float acc = a[8] * xout[(size_t)t * DMODEL + d];
#pragma unroll
    for (int n = 0; n < 8; ++n)
      acc = fmaf(a[n], xout[(size_t)(n * SEGLEN + SEGLEN - 1) * DMODEL + d], acc);
    g_ws[OFF_X + (size_t)t * DMODEL + d] = acc;
  }
}

extern "C" void kernel_launch(void* const* d_in, const int* in_sizes, int n_in,
                              void* d_out, int out_size, void* d_ws, size_t ws_size,
                              hipStream_t stream) {
  (void)in_sizes; (void)n_in; (void)out_size; (void)d_ws; (void)ws_size;
  const int* tokens = (const int*)d_in[0];

  detect_kernel<<<1, 64, 0, stream>>>((const unsigned int*)d_in[10]);

  struct { int idx; unsigned int off; int n; } conv_list[12] = {
    { 1, OFF_WEMB, 8 * 1024 * 768 },
    { 2, OFF_WWU,  4 * 768 * 768 },
    { 3, OFF_WIP,  4 * 3072 * 768 },
    { 4, OFF_WCW,  4 * 1536 * 4 },
    { 5, OFF_WCB,  4 * 1536 },
    { 6, OFF_WXP,  4 * 80 * 1536 },
    { 7, OFF_WDW,  4 * 1536 * 48 },
    { 8, OFF_WDB,  4 * 1536 },
    { 9, OFF_WAL,  4 * 1536 * 16 },
    {10, OFF_WDS,  4 * 1536 },
    {11, OFF_WOP,  4 * 768 * 1536 },
    {12, OFF_WHW,  8192 * 768 },
  };
  for (int i = 0; i < 12; ++i) {
    int blocks = (conv_list[i].n + 255) / 256;
    if (blocks > 2048) blocks = 2048;
    convert_kernel<<<blocks, 256, 0, stream>>>(d_in[conv_list[i].idx],
                                               conv_list[i].off, conv_list[i].n);
  }

  embed_kernel<<<T_LEN, 256, 0, stream>>>(tokens);

  for (int l = 0; l < 4; ++l) {
    unsigned int ip = OFF_WIP + (unsigned)l * DXZ * DMODEL;
    unsigned int xp = OFF_WXP + (unsigned)l * FDIM * DIN;
    unsigned int dw = OFF_WDW + (unsigned)l * DIN * DTRANK;
    unsigned int db = OFF_WDB + (unsigned)l * DIN;
    unsigned int al = OFF_WAL + (unsigned)l * DIN * NSTATE;
    unsigned int ds = OFF_WDS + (unsigned)l * DIN;
    unsigned int op = OFF_WOP + (unsigned)l * DMODEL * DIN;
    unsigned int wu = OFF_WWU + (unsigned)l * DMODEL * DMODEL;
    unsigned int cw = OFF_WCW + (unsigned)l * DIN * 4;
    unsigned int cb = OFF_WCB + (unsigned)l * DIN;

    // xz = x @ in_proj^T   (2048 x 3072, K=768)
    gemm_nt<0><<<dim3(48, 32), 256, 0, stream>>>(OFF_X, DMODEL, ip, DMODEL,
                                                 OFF_XZ, nullptr, DXZ,
                                                 T_LEN, DXZ, DMODEL, 0u);
    conv_silu_kernel<<<(T_LEN * DIN) / 256, 256, 0, stream>>>(cw, cb);
    // dbc = uc @ x_proj^T  (2048 x 80, K=1536)
    gemm_nt<0><<<dim3(2, 32), 256, 0, stream>>>(OFF_UC, DIN, xp, DIN,
                                                OFF_DBC, nullptr, FDIM,
                                                T_LEN, FDIM, DIN, 0u);
    // delta = softplus(dbc[:, :48] @ dt_w^T + dt_b)
    gemm_nt<1><<<dim3(24, 32), 256, 0, stream>>>(OFF_DBC, FDIM, dw, DTRANK,
                                                 OFF_DELTA, nullptr, DIN,
                                                 T_LEN, DIN, DTRANK, db);
    scan_kernel<<<DIN / 16, 256, 0, stream>>>(al, ds);
    // xout = y @ out_proj^T  (2048 x 768, K=1536)
    gemm_nt<0><<<dim3(12, 32), 256, 0, stream>>>(OFF_Y, DIN, op, DIN,
                                                 OFF_XOUT, nullptr, DMODEL,
                                                 T_LEN, DMODEL, DIN, 0u);
    // retention pieces (all read X before it is overwritten)
    mstack_kernel<<<NSEG, 256, 0, stream>>>();
    mcurrent_kernel<<<NSEG, 768, 0, stream>>>();
    gemm_nt<0><<<dim3(12, 32), 256, 0, stream>>>(OFF_X, DMODEL, wu, DMODEL,
                                                 OFF_URET, nullptr, DMODEL,
                                                 T_LEN, DMODEL, DMODEL, 0u);
    retention_kernel<<<T_LEN, 256, 0, stream>>>();
  }

  // logits = x @ head_w^T  (2048 x 8192, K=768) -> d_out (bf16 or f32)
  gemm_nt<2><<<dim3(128, 32), 256, 0, stream>>>(OFF_X, DMODEL, OFF_WHW, DMODEL,
                                                0u, d_out, NHEADV,
                                                T_LEN, NHEADV, DMODEL, 0u);
}

// Round 4
// 3481.087 us; speedup vs baseline: 2.5456x; 2.5456x over previous
//
#include <hip/hip_runtime.h>
#include <hip/hip_bf16.h>

// MCMambaLM: B=1, T=2048, D=768, K=8, V=1024, D_IN=1536, D_STATE=16,
// D_CONV=4, DT_RANK=48, L=4, SEG=256, n_seg=8.
// Input dtype (f32 vs bf16) detected at runtime from D_skip (== ones).
// All weights converted to f32 in static scratch; compute f32.
// Round 4: chunked parallel selective scan (32 chunks of 64) replaces the
// monolithic latency-bound scan (was 69% of runtime at 4.5% occupancy).

#define T_LEN   2048
#define DMODEL  768
#define DIN     1536
#define DXZ     3072
#define NSTATE  16
#define DTRANK  48
#define FDIM    80      // DT_RANK + 2*D_STATE
#define NSEG    8
#define SEGLEN  256
#define NHEADV  8192    // K*V
#define CH      64      // scan chunk length
#define NC      32      // number of chunks (T_LEN / CH)

// ---- activations (floats) ----
#define OFF_X     0u
#define OFF_XZ    1572864u
#define OFF_UC    7864320u
#define OFF_DBC   11010048u
#define OFF_DELTA 11173888u
#define OFF_Y     14319616u
#define OFF_XOUT  17465344u
#define OFF_URET  19038208u
#define OFF_MCUR  20611072u
#define OFF_MSTK  22183936u
// ---- converted f32 weights ----
#define OFF_WEMB  22190080u   // 8*1024*768
#define OFF_WWU   28481536u   // 4*768*768
#define OFF_WIP   30840832u   // 4*3072*768
#define OFF_WCW   40278016u   // 4*1536*4
#define OFF_WCB   40302592u   // 4*1536
#define OFF_WXP   40308736u   // 4*80*1536
#define OFF_WDW   40800256u   // 4*1536*48
#define OFF_WDB   41095168u   // 4*1536
#define OFF_WAL   41101312u   // 4*1536*16
#define OFF_WDS   41199616u   // 4*1536
#define OFF_WOP   41205760u   // 4*768*1536
#define OFF_WHW   45924352u   // 8192*768
// ---- scan scratch ----
#define OFF_SLOC  52215808u   // NC*DIN*16 local end states
#define OFF_HIN   53002240u   // NC*DIN*16 incoming states
#define OFF_CHP   53788672u   // NC*DIN chunk delta-sums
#define WS_TOTAL  53837824u   // ~205 MiB
__device__ __align__(16) float g_ws[WS_TOTAL];
__device__ unsigned int g_isbf16;

__device__ __forceinline__ float bf2f(unsigned short u) {
  union { unsigned int i; float f; } c; c.i = ((unsigned int)u) << 16; return c.f;
}
__device__ __forceinline__ unsigned short f2bf(float f) {
  union { float f; unsigned int i; } c; c.f = f;
  unsigned int lsb = (c.i >> 16) & 1u;
  unsigned int r = c.i + 0x7fffu + lsb;
  return (unsigned short)(r >> 16);
}
__device__ __forceinline__ float softplusf(float v) {
  return v > 0.f ? v + log1pf(expf(-v)) : log1pf(expf(v));
}

// ---------------- dtype detect ----------------
__global__ void detect_kernel(const unsigned int* __restrict__ dsk) {
  if (threadIdx.x == 0 && blockIdx.x == 0)
    g_isbf16 = (dsk[0] == 0x3F803F80u) ? 1u : 0u;
}

// ---------------- weight convert (bf16 or f32 -> f32 in g_ws) ----------------
__global__ __launch_bounds__(256) void convert_kernel(
    const void* __restrict__ src, unsigned int dstoff, int n) {
  int stride = gridDim.x * 256;
  bool isb = (g_isbf16 != 0u);
  for (int i = blockIdx.x * 256 + threadIdx.x; i < n; i += stride) {
    float v = isb ? bf2f(((const unsigned short*)src)[i])
                  : ((const float*)src)[i];
    g_ws[dstoff + i] = v;
  }
}

// ---------------- embedding ----------------
__global__ __launch_bounds__(256) void embed_kernel(const int* __restrict__ tokens) {
  int t = blockIdx.x;
  int tid = threadIdx.x;
  const float* __restrict__ emb = g_ws + OFF_WEMB;
  int tok[8];
#pragma unroll
  for (int k = 0; k < 8; ++k) tok[k] = tokens[t * 8 + k];
#pragma unroll
  for (int j = 0; j < 3; ++j) {
    int d = tid + j * 256;
    float s = 0.f;
#pragma unroll
    for (int k = 0; k < 8; ++k)
      s += emb[((size_t)k * 1024 + tok[k]) * DMODEL + d];
    g_ws[OFF_X + (size_t)t * DMODEL + d] = s;
  }
}

// ------- generic NT GEMM: C[M,N] = A[M,K] (f32 ws) * B[N,K]^T (f32 ws) -------
// EPI: 0 = store f32 to ws, 1 = softplus(acc + bias) f32 to ws,
//      2 = store to d_out (bf16 or f32 per g_isbf16)
template <int EPI>
__global__ __launch_bounds__(256) void gemm_nt(
    unsigned int aoff, int lda, unsigned int boff, int ldb,
    unsigned int coff, void* __restrict__ Cout, int ldc,
    int M, int N, int K, unsigned int biasoff) {
  const float* __restrict__ A = g_ws + aoff;
  const float* __restrict__ Bw = g_ws + boff;
  __shared__ float As[16][68];
  __shared__ float Bs[16][68];
  int tid = threadIdx.x;
  int bx = blockIdx.x, by = blockIdx.y;
  int tx = tid & 15, ty = tid >> 4;
  int lr = tid >> 2;          // 0..63 (tile row/col for loads)
  int lc = (tid & 3) * 4;     // 0,4,8,12 (k offset for loads)
  float acc[4][4] = {};
  for (int k0 = 0; k0 < K; k0 += 16) {
    const float* ap = A + (size_t)(by * 64 + lr) * lda + k0 + lc;
    float4 av = *reinterpret_cast<const float4*>(ap);
    As[lc + 0][lr] = av.x; As[lc + 1][lr] = av.y;
    As[lc + 2][lr] = av.z; As[lc + 3][lr] = av.w;
    int bn = bx * 64 + lr;
    float4 bv = make_float4(0.f, 0.f, 0.f, 0.f);
    if (bn < N)
      bv = *reinterpret_cast<const float4*>(Bw + (size_t)bn * ldb + k0 + lc);
    Bs[lc + 0][lr] = bv.x; Bs[lc + 1][lr] = bv.y;
    Bs[lc + 2][lr] = bv.z; Bs[lc + 3][lr] = bv.w;
    __syncthreads();
#pragma unroll
    for (int kk = 0; kk < 16; ++kk) {
      float4 a = *reinterpret_cast<const float4*>(&As[kk][ty * 4]);
      float4 b = *reinterpret_cast<const float4*>(&Bs[kk][tx * 4]);
      float ar[4] = {a.x, a.y, a.z, a.w};
      float br[4] = {b.x, b.y, b.z, b.w};
#pragma unroll
      for (int i = 0; i < 4; ++i)
#pragma unroll
        for (int j = 0; j < 4; ++j) acc[i][j] = fmaf(ar[i], br[j], acc[i][j]);
    }
    __syncthreads();
  }
  int m0 = by * 64 + ty * 4, n0 = bx * 64 + tx * 4;
  bool outb = (EPI == 2) && (g_isbf16 != 0u);
#pragma unroll
  for (int i = 0; i < 4; ++i) {
#pragma unroll
    for (int j = 0; j < 4; ++j) {
      int m = m0 + i, n = n0 + j;
      if (n < N) {
        float v = acc[i][j];
        if (EPI == 1) v = softplusf(v + g_ws[biasoff + n]);
        if (EPI == 2) {
          if (outb) ((unsigned short*)Cout)[(size_t)m * ldc + n] = f2bf(v);
          else      ((float*)Cout)[(size_t)m * ldc + n] = v;
        } else {
          g_ws[coff + (size_t)m * ldc + n] = v;
        }
      }
    }
  }
}

// ---------------- depthwise causal conv(4) + SiLU ----------------
__global__ __launch_bounds__(256) void conv_silu_kernel(
    unsigned int cwoff, unsigned int cboff) {
  int idx = blockIdx.x * 256 + threadIdx.x;   // 0 .. T*DIN-1
  int t = idx / DIN, e = idx - t * DIN;
  const float* __restrict__ xz = g_ws + OFF_XZ;
  const float* __restrict__ cw = g_ws + cwoff;
  float w0 = cw[e * 4 + 0], w1 = cw[e * 4 + 1];
  float w2 = cw[e * 4 + 2], w3 = cw[e * 4 + 3];
  float acc = g_ws[cboff + e];
  if (t >= 3) acc = fmaf(w0, xz[(size_t)(t - 3) * DXZ + e], acc);
  if (t >= 2) acc = fmaf(w1, xz[(size_t)(t - 2) * DXZ + e], acc);
  if (t >= 1) acc = fmaf(w2, xz[(size_t)(t - 1) * DXZ + e], acc);
  acc = fmaf(w3, xz[(size_t)t * DXZ + e], acc);
  float sig = 1.f / (1.f + __expf(-acc));
  g_ws[OFF_UC + idx] = acc * sig;
}

// ------- chunked selective scan, phase 1: local scan per chunk -------
// block: 16 channels x 16 states; grid (DIN/16, NC)
__global__ __launch_bounds__(256) void scan_phase1(unsigned int aloff) {
  int tid = threadIdx.x;
  int s = tid & 15;
  int e = blockIdx.x * 16 + (tid >> 4);
  int c = blockIdx.y;
  int t0 = c * CH;
  const float* __restrict__ delta = g_ws + OFF_DELTA;
  const float* __restrict__ uc    = g_ws + OFF_UC;
  const float* __restrict__ dbc   = g_ws + OFF_DBC;
  float a = -expf(g_ws[aloff + e * NSTATE + s]);   // A = -exp(A_log)
  float h = 0.f, P = 0.f;
  for (int i = 0; i < CH; ++i) {
    int t = t0 + i;
    float d = delta[(size_t)t * DIN + e];
    float u = uc[(size_t)t * DIN + e];
    float b = dbc[t * FDIM + DTRANK + s];
    float cc = dbc[t * FDIM + DTRANK + NSTATE + s];
    float dA = __expf(d * a);      // arg <= 0
    h = fmaf(dA, h, d * u * b);
    P += d;
    float yp = h * cc;
    yp += __shfl_xor(yp, 1);
    yp += __shfl_xor(yp, 2);
    yp += __shfl_xor(yp, 4);
    yp += __shfl_xor(yp, 8);
    if (s == 0) g_ws[OFF_Y + (size_t)t * DIN + e] = yp;   // partial (local)
  }
  g_ws[OFF_SLOC + ((size_t)c * DIN + e) * NSTATE + s] = h;
  if (s == 0) g_ws[OFF_CHP + c * DIN + e] = P;
}

// ------- phase 2: fold chunk states sequentially (tiny) -------
__global__ __launch_bounds__(256) void scan_phase2(unsigned int aloff) {
  int g = blockIdx.x * 256 + threadIdx.x;   // 0 .. DIN*16-1
  int e = g >> 4, s = g & 15;
  float a = -expf(g_ws[aloff + e * NSTATE + s]);
  float h = 0.f;
  for (int c = 0; c < NC; ++c) {
    g_ws[OFF_HIN + ((size_t)c * DIN + e) * NSTATE + s] = h;
    float S = g_ws[OFF_SLOC + ((size_t)c * DIN + e) * NSTATE + s];
    float P = g_ws[OFF_CHP + c * DIN + e];
    h = fmaf(__expf(a * P), h, S);
  }
}

// ------- phase 3: add inter-chunk correction + gating, finalize y -------
__global__ __launch_bounds__(256) void scan_phase3(unsigned int aloff,
                                                   unsigned int dsoff) {
  int tid = threadIdx.x;
  int s = tid & 15;
  int e = blockIdx.x * 16 + (tid >> 4);
  int c = blockIdx.y;
  int t0 = c * CH;
  const float* __restrict__ delta = g_ws + OFF_DELTA;
  const float* __restrict__ uc    = g_ws + OFF_UC;
  const float* __restrict__ dbc   = g_ws + OFF_DBC;
  const float* __restrict__ xz    = g_ws + OFF_XZ;
  float a = -expf(g_ws[aloff + e * NSTATE + s]);
  float dsk = g_ws[dsoff + e];
  float hin = g_ws[OFF_HIN + ((size_t)c * DIN + e) * NSTATE + s];
  float P = 0.f;
  for (int i = 0; i < CH; ++i) {
    int t = t0 + i;
    float d = delta[(size_t)t * DIN + e];
    P += d;
    float cc = dbc[t * FDIM + DTRANK + NSTATE + s];
    float yp = __expf(a * P) * hin * cc;
    yp += __shfl_xor(yp, 1);
    yp += __shfl_xor(yp, 2);
    yp += __shfl_xor(yp, 4);
    yp += __shfl_xor(yp, 8);
    if (s == 0) {
      float u = uc[(size_t)t * DIN + e];
      float z = xz[(size_t)t * DXZ + DIN + e];
      float y = g_ws[OFF_Y + (size_t)t * DIN + e] + yp;
      float sig = 1.f / (1.f + __expf(-z));
      g_ws[OFF_Y + (size_t)t * DIN + e] = (y + dsk * u) * z * sig;
    }
  }
}

// ---------------- segment mean (m_stack) ----------------
__global__ __launch_bounds__(256) void mstack_kernel() {
  int n = blockIdx.x;
  const float* __restrict__ x = g_ws + OFF_X;
  for (int d = threadIdx.x; d < DMODEL; d += 256) {
    float s = 0.f;
    for (int i = 0; i < SEGLEN; ++i)
      s += x[(size_t)(n * SEGLEN + i) * DMODEL + d];
    g_ws[OFF_MSTK + n * DMODEL + d] = s * (1.f / 256.f);
  }
}

// ---------------- running segment mean (m_current) ----------------
__global__ __launch_bounds__(768) void mcurrent_kernel() {
  int n = blockIdx.x;
  int d = threadIdx.x;
  const float* __restrict__ x = g_ws + OFF_X;
  float run = 0.f;
  for (int i = 0; i < SEGLEN; ++i) {
    size_t off = (size_t)(n * SEGLEN + i) * DMODEL + d;
    run += x[off];
    g_ws[OFF_MCUR + off] = run / (float)(i + 1);
  }
}

// ---------------- retention scores + softmax + combine (writes X) ---------
__global__ __launch_bounds__(256) void retention_kernel() {
  int t = blockIdx.x;
  int tid = threadIdx.x;
  const float* __restrict__ xout = g_ws + OFF_XOUT;
  const float* __restrict__ uret = g_ws + OFF_URET;
  const float* __restrict__ mcur = g_ws + OFF_MCUR;
  const float* __restrict__ mstk = g_ws + OFF_MSTK;
  __shared__ float red[4][9];
  __shared__ float attn_s[9];
  float p[9];
#pragma unroll
  for (int n = 0; n < 9; ++n) p[n] = 0.f;
#pragma unroll
  for (int j = 0; j < 3; ++j) {
    int d = tid + j * 256;
    float u = uret[(size_t)t * DMODEL + d];
    p[8] = fmaf(u, mcur[(size_t)t * DMODEL + d], p[8]);
#pragma unroll
    for (int n = 0; n < 8; ++n)
      p[n] = fmaf(u, mstk[n * DMODEL + d], p[n]);
  }
#pragma unroll
  for (int off = 32; off > 0; off >>= 1)
#pragma unroll
    for (int n = 0; n < 9; ++n) p[n] += __shfl_down(p[n], off, 64);
  int wave = tid >> 6;
  if ((tid & 63) == 0)
#pragma unroll
    for (int n = 0; n < 9; ++n) red[wave][n] = p[n];
  __syncthreads();
  if (tid == 0) {
    const float scale = 0.03608439182435161f;  // 1/sqrt(768)
    int seg = t >> 8;
    float sc[9], mx = -3.0e38f;
#pragma unroll
    for (int n = 0; n < 9; ++n) {
      float v = (red[0][n] + red[1][n] + red[2][n] + red[3][n]) * scale;
      if (n < 8 && n >= seg) v = -1e30f;   // keep only n < seg
      sc[n] = v;
      mx = fmaxf(mx, v);
    }
    float den = 0.f;
#pragma unroll
    for (int n = 0; n < 9; ++n) {
      float e = __expf(sc[n] - mx);
      sc[n] = e;
      den += e;
    }
    float inv = 1.f / den;
#pragma unroll
    for (int n = 0; n < 9; ++n) attn_s[n] = sc[n] * inv;
  }
  __syncthreads();
  float a[9];
#pragma unroll
  for (int n = 0; n < 9; ++n) a[n] = attn_s[n];
#pragma unroll
  for (int j = 0; j < 3; ++j) {
    int d = tid + j * 256;
    float acc = a[8] * xout[(size_t)t * DMODEL + d];
#pragma unroll
    for (int n = 0; n < 8; ++n)
      acc = fmaf(a[n], xout[(size_t)(n * SEGLEN + SEGLEN - 1) * DMODEL + d], acc);
    g_ws[OFF_X + (size_t)t * DMODEL + d] = acc;
  }
}

extern "C" void kernel_launch(void* const* d_in, const int* in_sizes, int n_in,
                              void* d_out, int out_size, void* d_ws, size_t ws_size,
                              hipStream_t stream) {
  (void)in_sizes; (void)n_in; (void)out_size; (void)d_ws; (void)ws_size;
  const int* tokens = (const int*)d_in[0];

  detect_kernel<<<1, 64, 0, stream>>>((const unsigned int*)d_in[10]);

  struct { int idx; unsigned int off; int n; } conv_list[12] = {
    { 1, OFF_WEMB, 8 * 1024 * 768 },
    { 2, OFF_WWU,  4 * 768 * 768 },
    { 3, OFF_WIP,  4 * 3072 * 768 },
    { 4, OFF_WCW,  4 * 1536 * 4 },
    { 5, OFF_WCB,  4 * 1536 },
    { 6, OFF_WXP,  4 * 80 * 1536 },
    { 7, OFF_WDW,  4 * 1536 * 48 },
    { 8, OFF_WDB,  4 * 1536 },
    { 9, OFF_WAL,  4 * 1536 * 16 },
    {10, OFF_WDS,  4 * 1536 },
    {11, OFF_WOP,  4 * 768 * 1536 },
    {12, OFF_WHW,  8192 * 768 },
  };
  for (int i = 0; i < 12; ++i) {
    int blocks = (conv_list[i].n + 255) / 256;
    if (blocks > 2048) blocks = 2048;
    convert_kernel<<<blocks, 256, 0, stream>>>(d_in[conv_list[i].idx],
                                               conv_list[i].off, conv_list[i].n);
  }

  embed_kernel<<<T_LEN, 256, 0, stream>>>(tokens);

  for (int l = 0; l < 4; ++l) {
    unsigned int ip = OFF_WIP + (unsigned)l * DXZ * DMODEL;
    unsigned int xp = OFF_WXP + (unsigned)l * FDIM * DIN;
    unsigned int dw = OFF_WDW + (unsigned)l * DIN * DTRANK;
    unsigned int db = OFF_WDB + (unsigned)l * DIN;
    unsigned int al = OFF_WAL + (unsigned)l * DIN * NSTATE;
    unsigned int ds = OFF_WDS + (unsigned)l * DIN;
    unsigned int op = OFF_WOP + (unsigned)l * DMODEL * DIN;
    unsigned int wu = OFF_WWU + (unsigned)l * DMODEL * DMODEL;
    unsigned int cw = OFF_WCW + (unsigned)l * DIN * 4;
    unsigned int cb = OFF_WCB + (unsigned)l * DIN;

    // xz = x @ in_proj^T   (2048 x 3072, K=768)
    gemm_nt<0><<<dim3(48, 32), 256, 0, stream>>>(OFF_X, DMODEL, ip, DMODEL,
                                                 OFF_XZ, nullptr, DXZ,
                                                 T_LEN, DXZ, DMODEL, 0u);
    conv_silu_kernel<<<(T_LEN * DIN) / 256, 256, 0, stream>>>(cw, cb);
    // dbc = uc @ x_proj^T  (2048 x 80, K=1536)
    gemm_nt<0><<<dim3(2, 32), 256, 0, stream>>>(OFF_UC, DIN, xp, DIN,
                                                OFF_DBC, nullptr, FDIM,
                                                T_LEN, FDIM, DIN, 0u);
    // delta = softplus(dbc[:, :48] @ dt_w^T + dt_b)
    gemm_nt<1><<<dim3(24, 32), 256, 0, stream>>>(OFF_DBC, FDIM, dw, DTRANK,
                                                 OFF_DELTA, nullptr, DIN,
                                                 T_LEN, DIN, DTRANK, db);
    // chunked selective scan
    scan_phase1<<<dim3(DIN / 16, NC), 256, 0, stream>>>(al);
    scan_phase2<<<(DIN * NSTATE) / 256, 256, 0, stream>>>(al);
    scan_phase3<<<dim3(DIN / 16, NC), 256, 0, stream>>>(al, ds);
    // xout = y @ out_proj^T  (2048 x 768, K=1536)
    gemm_nt<0><<<dim3(12, 32), 256, 0, stream>>>(OFF_Y, DIN, op, DIN,
                                                 OFF_XOUT, nullptr, DMODEL,
                                                 T_LEN, DMODEL, DIN, 0u);
    // retention pieces (all read X before it is overwritten)
    mstack_kernel<<<NSEG, 256, 0, stream>>>();
    mcurrent_kernel<<<NSEG, 768, 0, stream>>>();
    gemm_nt<0><<<dim3(12, 32), 256, 0, stream>>>(OFF_X, DMODEL, wu, DMODEL,
                                                 OFF_URET, nullptr, DMODEL,
                                                 T_LEN, DMODEL, DMODEL, 0u);
    retention_kernel<<<T_LEN, 256, 0, stream>>>();
  }

  // logits = x @ head_w^T  (2048 x 8192, K=768) -> d_out (bf16 or f32)
  gemm_nt<2><<<dim3(128, 32), 256, 0, stream>>>(OFF_X, DMODEL, OFF_WHW, DMODEL,
                                                0u, d_out, NHEADV,
                                                T_LEN, NHEADV, DMODEL, 0u);
}

// Round 5
// 2976.403 us; speedup vs baseline: 2.9773x; 1.1696x over previous
//
#include <hip/hip_runtime.h>
#include <hip/hip_bf16.h>

// MCMambaLM: B=1, T=2048, D=768, K=8, V=1024, D_IN=1536, D_STATE=16,
// D_CONV=4, DT_RANK=48, L=4, SEG=256, n_seg=8.
// Round 5: big GEMMs (in_proj/out_proj/W_u/head) -> MFMA bf16 split (hi+lo),
// f32-quality precision at 3 MFMA per product term. Small GEMMs stay f32 VALU.

#define T_LEN   2048
#define DMODEL  768
#define DIN     1536
#define DXZ     3072
#define NSTATE  16
#define DTRANK  48
#define FDIM    80
#define NSEG    8
#define SEGLEN  256
#define NHEADV  8192
#define CH      64
#define NC      32

// ---- f32 scratch ----
#define OFF_X     0u
#define OFF_XZ    1572864u
#define OFF_UC    7864320u
#define OFF_DBC   11010048u
#define OFF_DELTA 11173888u
#define OFF_Y     14319616u
#define OFF_XOUT  17465344u
#define OFF_URET  19038208u
#define OFF_MCUR  20611072u
#define OFF_MSTK  22183936u
#define OFF_WEMB  22190080u   // 8*1024*768
#define OFF_WCW   28481536u   // 4*1536*4
#define OFF_WCB   28506112u   // 4*1536
#define OFF_WXP   28512256u   // 4*80*1536
#define OFF_WDW   29003776u   // 4*1536*48
#define OFF_WDB   29298688u   // 4*1536
#define OFF_WAL   29304832u   // 4*1536*16
#define OFF_WDS   29403136u   // 4*1536
#define OFF_SLOC  29409280u   // NC*DIN*16
#define OFF_HIN   30195712u
#define OFF_CHP   30982144u   // NC*DIN
#define WS_TOTAL  31031296u
__device__ __align__(16) float g_ws[WS_TOTAL];

// ---- bf16 hi/lo scratch (ushort elems) ----
#define BF_XHI   0u          // 2048*768
#define BF_XLO   1572864u
#define BF_YHI   3145728u    // 2048*1536
#define BF_YLO   6291456u
#define BF_IPHI  9437184u    // 4*3072*768
#define BF_IPLO  18874368u
#define BF_OPHI  28311552u   // 4*768*1536
#define BF_OPLO  33030144u
#define BF_WUHI  37748736u   // 4*768*768
#define BF_WULO  40108032u
#define BF_HWHI  42467328u   // 8192*768
#define BF_HWLO  48758784u
#define BF_TOTAL 55050240u
__device__ __align__(16) unsigned short g_bf[BF_TOTAL];
__device__ unsigned int g_isbf16;

typedef __attribute__((ext_vector_type(8))) short bf16x8;
typedef __attribute__((ext_vector_type(4))) float f32x4;

__device__ __forceinline__ float bf2f(unsigned short u) {
  union { unsigned int i; float f; } c; c.i = ((unsigned int)u) << 16; return c.f;
}
__device__ __forceinline__ unsigned short f2bf(float f) {
  union { float f; unsigned int i; } c; c.f = f;
  unsigned int lsb = (c.i >> 16) & 1u;
  unsigned int r = c.i + 0x7fffu + lsb;
  return (unsigned short)(r >> 16);
}
__device__ __forceinline__ float softplusf(float v) {
  return v > 0.f ? v + log1pf(expf(-v)) : log1pf(expf(v));
}

// ---------------- dtype detect ----------------
__global__ void detect_kernel(const unsigned int* __restrict__ dsk) {
  if (threadIdx.x == 0 && blockIdx.x == 0)
    g_isbf16 = (dsk[0] == 0x3F803F80u) ? 1u : 0u;
}

// ---------------- convert (bf16 or f32 -> f32) ----------------
__global__ __launch_bounds__(256) void convert_kernel(
    const void* __restrict__ src, unsigned int dstoff, int n) {
  int stride = gridDim.x * 256;
  bool isb = (g_isbf16 != 0u);
  for (int i = blockIdx.x * 256 + threadIdx.x; i < n; i += stride) {
    float v = isb ? bf2f(((const unsigned short*)src)[i])
                  : ((const float*)src)[i];
    g_ws[dstoff + i] = v;
  }
}

// ---------------- weight split: d_in -> (hi, lo) bf16 ----------------
__global__ __launch_bounds__(256) void splitw_kernel(
    const void* __restrict__ src, unsigned hioff, unsigned looff, int n) {
  int stride = gridDim.x * 256;
  bool isb = (g_isbf16 != 0u);
  for (int i = blockIdx.x * 256 + threadIdx.x; i < n; i += stride) {
    float v = isb ? bf2f(((const unsigned short*)src)[i])
                  : ((const float*)src)[i];
    unsigned short h = f2bf(v);
    g_bf[hioff + i] = h;
    g_bf[looff + i] = f2bf(v - bf2f(h));
  }
}

// ---------------- activation split: g_ws f32 -> (hi, lo) bf16 ----------------
__global__ __launch_bounds__(256) void split_act(
    unsigned srcoff, unsigned hioff, unsigned looff, int n) {
  int i = blockIdx.x * 256 + threadIdx.x;
  if (i >= n) return;
  float v = g_ws[srcoff + i];
  unsigned short h = f2bf(v);
  g_bf[hioff + i] = h;
  g_bf[looff + i] = f2bf(v - bf2f(h));
}

// ---------------- embedding ----------------
__global__ __launch_bounds__(256) void embed_kernel(const int* __restrict__ tokens) {
  int t = blockIdx.x;
  int tid = threadIdx.x;
  const float* __restrict__ emb = g_ws + OFF_WEMB;
  int tok[8];
#pragma unroll
  for (int k = 0; k < 8; ++k) tok[k] = tokens[t * 8 + k];
#pragma unroll
  for (int j = 0; j < 3; ++j) {
    int d = tid + j * 256;
    float s = 0.f;
#pragma unroll
    for (int k = 0; k < 8; ++k)
      s += emb[((size_t)k * 1024 + tok[k]) * DMODEL + d];
    g_ws[OFF_X + (size_t)t * DMODEL + d] = s;
  }
}

// ------- MFMA split-bf16 GEMM: C[M,N] = A[M,K] * W[N,K]^T -------
// A,W given as bf16 hi/lo pairs in g_bf (row-major, leading dim K).
// Block tile 128(M) x 64(N), BK=32; 4 waves, each 32 rows x 64 cols.
// EPI: 0 = store f32 to g_ws; 2 = store to Cout (bf16/f32 per g_isbf16).
template <int EPI>
__global__ __launch_bounds__(256) void gemm_mfma(
    unsigned ahio, unsigned aloo, unsigned whio, unsigned wloo,
    unsigned coff, void* __restrict__ Cout, int ldc, int K) {
  __shared__ __align__(16) unsigned short sA[2][128 * 40];  // hi, lo; rows padded
  __shared__ __align__(16) unsigned short sW[2][64 * 40];
  const unsigned short* __restrict__ ahi = g_bf + ahio;
  const unsigned short* __restrict__ alo = g_bf + aloo;
  const unsigned short* __restrict__ whi = g_bf + whio;
  const unsigned short* __restrict__ wlo = g_bf + wloo;
  int tid = threadIdx.x;
  int bm = blockIdx.y * 128, bn = blockIdx.x * 64;
  int w = tid >> 6, lane = tid & 63;
  int lm = lane & 15, quad = lane >> 4;
  f32x4 acc[2][4] = {};
  for (int k0 = 0; k0 < K; k0 += 32) {
    // stage A tiles (hi+lo): 2 x 128 rows x 32 shorts, 16B chunks
    for (int c = tid; c < 1024; c += 256) {
      int buf = c >> 9, cc = c & 511;
      int row = cc >> 2, ko = (cc & 3) * 8;
      const unsigned short* src = (buf ? alo : ahi) + (size_t)(bm + row) * K + k0 + ko;
      *(uint4*)&sA[buf][row * 40 + ko] = *(const uint4*)src;
    }
    // stage W tiles (hi+lo): 2 x 64 rows x 32 shorts
    for (int c = tid; c < 512; c += 256) {
      int buf = c >> 8, cc = c & 255;
      int row = cc >> 2, ko = (cc & 3) * 8;
      const unsigned short* src = (buf ? wlo : whi) + (size_t)(bn + row) * K + k0 + ko;
      *(uint4*)&sW[buf][row * 40 + ko] = *(const uint4*)src;
    }
    __syncthreads();
    bf16x8 ah[2], al[2], wh[4], wl[4];
#pragma unroll
    for (int mi = 0; mi < 2; ++mi) {
      int r = w * 32 + mi * 16 + lm;
      ah[mi] = *(const bf16x8*)&sA[0][r * 40 + quad * 8];
      al[mi] = *(const bf16x8*)&sA[1][r * 40 + quad * 8];
    }
#pragma unroll
    for (int ni = 0; ni < 4; ++ni) {
      int r = ni * 16 + lm;
      wh[ni] = *(const bf16x8*)&sW[0][r * 40 + quad * 8];
      wl[ni] = *(const bf16x8*)&sW[1][r * 40 + quad * 8];
    }
#pragma unroll
    for (int mi = 0; mi < 2; ++mi)
#pragma unroll
      for (int ni = 0; ni < 4; ++ni) {
        acc[mi][ni] = __builtin_amdgcn_mfma_f32_16x16x32_bf16(ah[mi], wh[ni], acc[mi][ni], 0, 0, 0);
        acc[mi][ni] = __builtin_amdgcn_mfma_f32_16x16x32_bf16(ah[mi], wl[ni], acc[mi][ni], 0, 0, 0);
        acc[mi][ni] = __builtin_amdgcn_mfma_f32_16x16x32_bf16(al[mi], wh[ni], acc[mi][ni], 0, 0, 0);
      }
    __syncthreads();
  }
  bool outb = (EPI == 2) && (g_isbf16 != 0u);
#pragma unroll
  for (int mi = 0; mi < 2; ++mi)
#pragma unroll
    for (int ni = 0; ni < 4; ++ni)
#pragma unroll
      for (int r = 0; r < 4; ++r) {
        int gm = bm + w * 32 + mi * 16 + quad * 4 + r;
        int gn = bn + ni * 16 + lm;
        float v = acc[mi][ni][r];
        if (EPI == 2) {
          if (outb) ((unsigned short*)Cout)[(size_t)gm * ldc + gn] = f2bf(v);
          else      ((float*)Cout)[(size_t)gm * ldc + gn] = v;
        } else {
          g_ws[coff + (size_t)gm * ldc + gn] = v;
        }
      }
}

// ------- small f32 NT GEMM (kept for dbc / dt) -------
// EPI: 0 = store f32 to ws, 1 = softplus(acc + bias) f32 to ws
template <int EPI>
__global__ __launch_bounds__(256) void gemm_nt(
    unsigned int aoff, int lda, unsigned int boff, int ldb,
    unsigned int coff, int ldc, int M, int N, int K, unsigned int biasoff) {
  const float* __restrict__ A = g_ws + aoff;
  const float* __restrict__ Bw = g_ws + boff;
  __shared__ float As[16][68];
  __shared__ float Bs[16][68];
  int tid = threadIdx.x;
  int bx = blockIdx.x, by = blockIdx.y;
  int tx = tid & 15, ty = tid >> 4;
  int lr = tid >> 2;
  int lc = (tid & 3) * 4;
  float acc[4][4] = {};
  for (int k0 = 0; k0 < K; k0 += 16) {
    const float* ap = A + (size_t)(by * 64 + lr) * lda + k0 + lc;
    float4 av = *reinterpret_cast<const float4*>(ap);
    As[lc + 0][lr] = av.x; As[lc + 1][lr] = av.y;
    As[lc + 2][lr] = av.z; As[lc + 3][lr] = av.w;
    int bn = bx * 64 + lr;
    float4 bv = make_float4(0.f, 0.f, 0.f, 0.f);
    if (bn < N)
      bv = *reinterpret_cast<const float4*>(Bw + (size_t)bn * ldb + k0 + lc);
    Bs[lc + 0][lr] = bv.x; Bs[lc + 1][lr] = bv.y;
    Bs[lc + 2][lr] = bv.z; Bs[lc + 3][lr] = bv.w;
    __syncthreads();
#pragma unroll
    for (int kk = 0; kk < 16; ++kk) {
      float4 a = *reinterpret_cast<const float4*>(&As[kk][ty * 4]);
      float4 b = *reinterpret_cast<const float4*>(&Bs[kk][tx * 4]);
      float ar[4] = {a.x, a.y, a.z, a.w};
      float br[4] = {b.x, b.y, b.z, b.w};
#pragma unroll
      for (int i = 0; i < 4; ++i)
#pragma unroll
        for (int j = 0; j < 4; ++j) acc[i][j] = fmaf(ar[i], br[j], acc[i][j]);
    }
    __syncthreads();
  }
  int m0 = by * 64 + ty * 4, n0 = bx * 64 + tx * 4;
#pragma unroll
  for (int i = 0; i < 4; ++i) {
#pragma unroll
    for (int j = 0; j < 4; ++j) {
      int m = m0 + i, n = n0 + j;
      if (n < N) {
        float v = acc[i][j];
        if (EPI == 1) v = softplusf(v + g_ws[biasoff + n]);
        g_ws[coff + (size_t)m * ldc + n] = v;
      }
    }
  }
}

// ---------------- depthwise causal conv(4) + SiLU ----------------
__global__ __launch_bounds__(256) void conv_silu_kernel(
    unsigned int cwoff, unsigned int cboff) {
  int idx = blockIdx.x * 256 + threadIdx.x;
  int t = idx / DIN, e = idx - t * DIN;
  const float* __restrict__ xz = g_ws + OFF_XZ;
  const float* __restrict__ cw = g_ws + cwoff;
  float w0 = cw[e * 4 + 0], w1 = cw[e * 4 + 1];
  float w2 = cw[e * 4 + 2], w3 = cw[e * 4 + 3];
  float acc = g_ws[cboff + e];
  if (t >= 3) acc = fmaf(w0, xz[(size_t)(t - 3) * DXZ + e], acc);
  if (t >= 2) acc = fmaf(w1, xz[(size_t)(t - 2) * DXZ + e], acc);
  if (t >= 1) acc = fmaf(w2, xz[(size_t)(t - 1) * DXZ + e], acc);
  acc = fmaf(w3, xz[(size_t)t * DXZ + e], acc);
  float sig = 1.f / (1.f + __expf(-acc));
  g_ws[OFF_UC + idx] = acc * sig;
}

// ------- chunked selective scan -------
__global__ __launch_bounds__(256) void scan_phase1(unsigned int aloff) {
  int tid = threadIdx.x;
  int s = tid & 15;
  int e = blockIdx.x * 16 + (tid >> 4);
  int c = blockIdx.y;
  int t0 = c * CH;
  const float* __restrict__ delta = g_ws + OFF_DELTA;
  const float* __restrict__ uc    = g_ws + OFF_UC;
  const float* __restrict__ dbc   = g_ws + OFF_DBC;
  float a = -expf(g_ws[aloff + e * NSTATE + s]);
  float h = 0.f, P = 0.f;
  for (int i = 0; i < CH; ++i) {
    int t = t0 + i;
    float d = delta[(size_t)t * DIN + e];
    float u = uc[(size_t)t * DIN + e];
    float b = dbc[t * FDIM + DTRANK + s];
    float cc = dbc[t * FDIM + DTRANK + NSTATE + s];
    float dA = __expf(d * a);
    h = fmaf(dA, h, d * u * b);
    P += d;
    float yp = h * cc;
    yp += __shfl_xor(yp, 1);
    yp += __shfl_xor(yp, 2);
    yp += __shfl_xor(yp, 4);
    yp += __shfl_xor(yp, 8);
    if (s == 0) g_ws[OFF_Y + (size_t)t * DIN + e] = yp;
  }
  g_ws[OFF_SLOC + ((size_t)c * DIN + e) * NSTATE + s] = h;
  if (s == 0) g_ws[OFF_CHP + c * DIN + e] = P;
}

__global__ __launch_bounds__(256) void scan_phase2(unsigned int aloff) {
  int g = blockIdx.x * 256 + threadIdx.x;
  int e = g >> 4, s = g & 15;
  float a = -expf(g_ws[aloff + e * NSTATE + s]);
  float h = 0.f;
  for (int c = 0; c < NC; ++c) {
    g_ws[OFF_HIN + ((size_t)c * DIN + e) * NSTATE + s] = h;
    float S = g_ws[OFF_SLOC + ((size_t)c * DIN + e) * NSTATE + s];
    float P = g_ws[OFF_CHP + c * DIN + e];
    h = fmaf(__expf(a * P), h, S);
  }
}

__global__ __launch_bounds__(256) void scan_phase3(unsigned int aloff,
                                                   unsigned int dsoff) {
  int tid = threadIdx.x;
  int s = tid & 15;
  int e = blockIdx.x * 16 + (tid >> 4);
  int c = blockIdx.y;
  int t0 = c * CH;
  const float* __restrict__ delta = g_ws + OFF_DELTA;
  const float* __restrict__ uc    = g_ws + OFF_UC;
  const float* __restrict__ dbc   = g_ws + OFF_DBC;
  const float* __restrict__ xz    = g_ws + OFF_XZ;
  float a = -expf(g_ws[aloff + e * NSTATE + s]);
  float dsk = g_ws[dsoff + e];
  float hin = g_ws[OFF_HIN + ((size_t)c * DIN + e) * NSTATE + s];
  float P = 0.f;
  for (int i = 0; i < CH; ++i) {
    int t = t0 + i;
    float d = delta[(size_t)t * DIN + e];
    P += d;
    float cc = dbc[t * FDIM + DTRANK + NSTATE + s];
    float yp = __expf(a * P) * hin * cc;
    yp += __shfl_xor(yp, 1);
    yp += __shfl_xor(yp, 2);
    yp += __shfl_xor(yp, 4);
    yp += __shfl_xor(yp, 8);
    if (s == 0) {
      float u = uc[(size_t)t * DIN + e];
      float z = xz[(size_t)t * DXZ + DIN + e];
      float y = g_ws[OFF_Y + (size_t)t * DIN + e] + yp;
      float sig = 1.f / (1.f + __expf(-z));
      g_ws[OFF_Y + (size_t)t * DIN + e] = (y + dsk * u) * z * sig;
    }
  }
}

// ---------------- segment mean (m_stack) ----------------
__global__ __launch_bounds__(256) void mstack_kernel() {
  int n = blockIdx.x;
  const float* __restrict__ x = g_ws + OFF_X;
  for (int d = threadIdx.x; d < DMODEL; d += 256) {
    float s = 0.f;
    for (int i = 0; i < SEGLEN; ++i)
      s += x[(size_t)(n * SEGLEN + i) * DMODEL + d];
    g_ws[OFF_MSTK + n * DMODEL + d] = s * (1.f / 256.f);
  }
}

// ---------------- running segment mean (m_current) ----------------
__global__ __launch_bounds__(768) void mcurrent_kernel() {
  int n = blockIdx.x;
  int d = threadIdx.x;
  const float* __restrict__ x = g_ws + OFF_X;
  float run = 0.f;
  for (int i = 0; i < SEGLEN; ++i) {
    size_t off = (size_t)(n * SEGLEN + i) * DMODEL + d;
    run += x[off];
    g_ws[OFF_MCUR + off] = run / (float)(i + 1);
  }
}

// ---------------- retention ----------------
__global__ __launch_bounds__(256) void retention_kernel() {
  int t = blockIdx.x;
  int tid = threadIdx.x;
  const float* __restrict__ xout = g_ws + OFF_XOUT;
  const float* __restrict__ uret = g_ws + OFF_URET;
  const float* __restrict__ mcur = g_ws + OFF_MCUR;
  const float* __restrict__ mstk = g_ws + OFF_MSTK;
  __shared__ float red[4][9];
  __shared__ float attn_s[9];
  float p[9];
#pragma unroll
  for (int n = 0; n < 9; ++n) p[n] = 0.f;
#pragma unroll
  for (int j = 0; j < 3; ++j) {
    int d = tid + j * 256;
    float u = uret[(size_t)t * DMODEL + d];
    p[8] = fmaf(u, mcur[(size_t)t * DMODEL + d], p[8]);
#pragma unroll
    for (int n = 0; n < 8; ++n)
      p[n] = fmaf(u, mstk[n * DMODEL + d], p[n]);
  }
#pragma unroll
  for (int off = 32; off > 0; off >>= 1)
#pragma unroll
    for (int n = 0; n < 9; ++n) p[n] += __shfl_down(p[n], off, 64);
  int wave = tid >> 6;
  if ((tid & 63) == 0)
#pragma unroll
    for (int n = 0; n < 9; ++n) red[wave][n] = p[n];
  __syncthreads();
  if (tid == 0) {
    const float scale = 0.03608439182435161f;
    int seg = t >> 8;
    float sc[9], mx = -3.0e38f;
#pragma unroll
    for (int n = 0; n < 9; ++n) {
      float v = (red[0][n] + red[1][n] + red[2][n] + red[3][n]) * scale;
      if (n < 8 && n >= seg) v = -1e30f;
      sc[n] = v;
      mx = fmaxf(mx, v);
    }
    float den = 0.f;
#pragma unroll
    for (int n = 0; n < 9; ++n) {
      float e = __expf(sc[n] - mx);
      sc[n] = e;
      den += e;
    }
    float inv = 1.f / den;
#pragma unroll
    for (int n = 0; n < 9; ++n) attn_s[n] = sc[n] * inv;
  }
  __syncthreads();
  float a[9];
#pragma unroll
  for (int n = 0; n < 9; ++n) a[n] = attn_s[n];
#pragma unroll
  for (int j = 0; j < 3; ++j) {
    int d = tid + j * 256;
    float acc = a[8] * xout[(size_t)t * DMODEL + d];
#pragma unroll
    for (int n = 0; n < 8; ++n)
      acc = fmaf(a[n], xout[(size_t)(n * SEGLEN + SEGLEN - 1) * DMODEL + d], acc);
    g_ws[OFF_X + (size_t)t * DMODEL + d] = acc;
  }
}

extern "C" void kernel_launch(void* const* d_in, const int* in_sizes, int n_in,
                              void* d_out, int out_size, void* d_ws, size_t ws_size,
                              hipStream_t stream) {
  (void)in_sizes; (void)n_in; (void)out_size; (void)d_ws; (void)ws_size;
  const int* tokens = (const int*)d_in[0];

  detect_kernel<<<1, 64, 0, stream>>>((const unsigned int*)d_in[10]);

  // f32 conversions (small weights + embedding)
  struct { int idx; unsigned int off; int n; } conv_list[8] = {
    { 1, OFF_WEMB, 8 * 1024 * 768 },
    { 4, OFF_WCW,  4 * 1536 * 4 },
    { 5, OFF_WCB,  4 * 1536 },
    { 6, OFF_WXP,  4 * 80 * 1536 },
    { 7, OFF_WDW,  4 * 1536 * 48 },
    { 8, OFF_WDB,  4 * 1536 },
    { 9, OFF_WAL,  4 * 1536 * 16 },
    {10, OFF_WDS,  4 * 1536 },
  };
  for (int i = 0; i < 8; ++i) {
    int blocks = (conv_list[i].n + 255) / 256;
    if (blocks > 4096) blocks = 4096;
    convert_kernel<<<blocks, 256, 0, stream>>>(d_in[conv_list[i].idx],
                                               conv_list[i].off, conv_list[i].n);
  }
  // big-weight hi/lo splits
  splitw_kernel<<<4096, 256, 0, stream>>>(d_in[3],  BF_IPHI, BF_IPLO, 4 * 3072 * 768);
  splitw_kernel<<<4096, 256, 0, stream>>>(d_in[11], BF_OPHI, BF_OPLO, 4 * 768 * 1536);
  splitw_kernel<<<4096, 256, 0, stream>>>(d_in[2],  BF_WUHI, BF_WULO, 4 * 768 * 768);
  splitw_kernel<<<4096, 256, 0, stream>>>(d_in[12], BF_HWHI, BF_HWLO, 8192 * 768);

  embed_kernel<<<T_LEN, 256, 0, stream>>>(tokens);

  for (int l = 0; l < 4; ++l) {
    unsigned int xp = OFF_WXP + (unsigned)l * FDIM * DIN;
    unsigned int dw = OFF_WDW + (unsigned)l * DIN * DTRANK;
    unsigned int db = OFF_WDB + (unsigned)l * DIN;
    unsigned int al = OFF_WAL + (unsigned)l * DIN * NSTATE;
    unsigned int ds = OFF_WDS + (unsigned)l * DIN;
    unsigned int cw = OFF_WCW + (unsigned)l * DIN * 4;
    unsigned int cb = OFF_WCB + (unsigned)l * DIN;
    unsigned int iphi = BF_IPHI + (unsigned)l * DXZ * DMODEL;
    unsigned int iplo = BF_IPLO + (unsigned)l * DXZ * DMODEL;
    unsigned int ophi = BF_OPHI + (unsigned)l * DMODEL * DIN;
    unsigned int oplo = BF_OPLO + (unsigned)l * DMODEL * DIN;
    unsigned int wuhi = BF_WUHI + (unsigned)l * DMODEL * DMODEL;
    unsigned int wulo = BF_WULO + (unsigned)l * DMODEL * DMODEL;

    // split x -> bf16 hi/lo (used by in_proj and W_u)
    split_act<<<(T_LEN * DMODEL) / 256, 256, 0, stream>>>(OFF_X, BF_XHI, BF_XLO,
                                                          T_LEN * DMODEL);
    // xz = x @ in_proj^T   (2048 x 3072, K=768)
    gemm_mfma<0><<<dim3(DXZ / 64, T_LEN / 128), 256, 0, stream>>>(
        BF_XHI, BF_XLO, iphi, iplo, OFF_XZ, nullptr, DXZ, DMODEL);
    conv_silu_kernel<<<(T_LEN * DIN) / 256, 256, 0, stream>>>(cw, cb);
    // dbc = uc @ x_proj^T  (2048 x 80, K=1536)
    gemm_nt<0><<<dim3(2, 32), 256, 0, stream>>>(OFF_UC, DIN, xp, DIN,
                                                OFF_DBC, FDIM, T_LEN, FDIM, DIN, 0u);
    // delta = softplus(dbc[:, :48] @ dt_w^T + dt_b)
    gemm_nt<1><<<dim3(24, 32), 256, 0, stream>>>(OFF_DBC, FDIM, dw, DTRANK,
                                                 OFF_DELTA, DIN, T_LEN, DIN, DTRANK, db);
    // chunked selective scan
    scan_phase1<<<dim3(DIN / 16, NC), 256, 0, stream>>>(al);
    scan_phase2<<<(DIN * NSTATE) / 256, 256, 0, stream>>>(al);
    scan_phase3<<<dim3(DIN / 16, NC), 256, 0, stream>>>(al, ds);
    // split y; xout = y @ out_proj^T  (2048 x 768, K=1536)
    split_act<<<(T_LEN * DIN) / 256, 256, 0, stream>>>(OFF_Y, BF_YHI, BF_YLO,
                                                       T_LEN * DIN);
    gemm_mfma<0><<<dim3(DMODEL / 64, T_LEN / 128), 256, 0, stream>>>(
        BF_YHI, BF_YLO, ophi, oplo, OFF_XOUT, nullptr, DMODEL, DIN);
    // retention pieces
    mstack_kernel<<<NSEG, 256, 0, stream>>>();
    mcurrent_kernel<<<NSEG, 768, 0, stream>>>();
    gemm_mfma<0><<<dim3(DMODEL / 64, T_LEN / 128), 256, 0, stream>>>(
        BF_XHI, BF_XLO, wuhi, wulo, OFF_URET, nullptr, DMODEL, DMODEL);
    retention_kernel<<<T_LEN, 256, 0, stream>>>();
  }

  // logits = x @ head_w^T  (2048 x 8192, K=768) -> d_out
  split_act<<<(T_LEN * DMODEL) / 256, 256, 0, stream>>>(OFF_X, BF_XHI, BF_XLO,
                                                        T_LEN * DMODEL);
  gemm_mfma<2><<<dim3(NHEADV / 64, T_LEN / 128), 256, 0, stream>>>(
      BF_XHI, BF_XLO, BF_HWHI, BF_HWLO, 0u, d_out, NHEADV, DMODEL);
}